// Round 15
// baseline (315.634 us; speedup 1.0000x reference)
//
#include <hip/hip_runtime.h>
#include <cstdint>
#include <cstddef>

#define NEG_SLOPE 0.2f

typedef _Float16 f16x8 __attribute__((ext_vector_type(8)));
typedef _Float16 f16x2 __attribute__((ext_vector_type(2)));
typedef float    f32x4 __attribute__((ext_vector_type(4)));
typedef float    f32x2 __attribute__((ext_vector_type(2)));

__device__ __forceinline__ float leaky(float x){ return x > 0.f ? x : NEG_SLOPE * x; }
__device__ __forceinline__ float elu(float x){ return x > 0.f ? x : __expf(x) - 1.f; }

// async global->LDS, 16B per lane (lds base must be wave-uniform; HW writes base + lane*16)
__device__ __forceinline__ void gl_lds16(const void* g, void* l) {
    __builtin_amdgcn_global_load_lds((const __attribute__((address_space(1))) unsigned int*)g,
                                     (__attribute__((address_space(3))) unsigned int*)l, 16, 0, 0);
}

// ============ front: weight split + parallel attn fold + CSR count + graph bounds ============
__global__ __launch_bounds__(256) void k_front(const float* __restrict__ W1,
                                               const float* __restrict__ W2,
                                               const float* __restrict__ as1,
                                               const float* __restrict__ ad1,
                                               _Float16* __restrict__ W1hi, _Float16* __restrict__ W1lo,
                                               _Float16* __restrict__ W2hi, _Float16* __restrict__ W2lo,
                                               float* __restrict__ w_s, float* __restrict__ w_d,
                                               const int* __restrict__ ei, int* __restrict__ deg,
                                               unsigned short* __restrict__ rank,
                                               const int* __restrict__ batch, int* __restrict__ gstart,
                                               int E, int Ep, int N, int G, int nbc)
{
    int b = blockIdx.x;
    if (b < 512) {
        const float* src = (b < 256) ? W1 : W2;
        _Float16* hi = (b < 256) ? W1hi : W2hi;
        _Float16* lo = (b < 256) ? W1lo : W2lo;
        int i = ((b & 255) << 8) + threadIdx.x;
        float v = src[i];
        _Float16 h = (_Float16)v;
        hi[i] = h;
        lo[i] = (_Float16)(v - (float)h);
    } else if (b < 576) {
        // attn fold, c-parallel: block covers (h, 8 c-values); w_s/w_d are pre-zeroed.
        int b2 = b - 512;
        int h  = b2 >> 4;           // 0..3
        int cg = b2 & 15;           // 0..15 -> c in [cg*8, cg*8+8)
        int k  = threadIdx.x & 127;
        int c0 = cg * 8 + (threadIdx.x >> 7) * 4;
        float s = 0.f, d = 0.f;
        #pragma unroll
        for (int cc = 0; cc < 4; ++cc) {
            int c = c0 + cc;
            float w = W1[((size_t)(h * 128 + c)) * 128 + k];
            s += as1[h * 128 + c] * w;
            d += ad1[h * 128 + c] * w;
        }
        atomicAdd(&w_s[h * 128 + k], s);
        atomicAdd(&w_d[h * 128 + k], d);
    } else if (b < 576 + nbc) {
        int e = (b - 576) * 256 + threadIdx.x;
        if (e >= Ep) return;
        int dst = (e < E) ? ei[E + e] : (e - E);
        rank[e] = (unsigned short)atomicAdd(&deg[dst], 1);
    } else {
        int n = (b - 576 - nbc) * 256 + threadIdx.x;
        if (n >= N) return;
        int bb = batch[n];
        int prev = (n == 0) ? -1 : batch[n - 1];
        for (int g = prev + 1; g <= bb; ++g) gstart[g] = n;
        if (n == N - 1)
            for (int g = bb + 1; g <= G; ++g) gstart[g] = N;
    }
}

// ============ scanA (block-local scan of degrees) || layer-1 attn logits + fp16 x ============
// start[] holds BLOCK-LOCAL exclusive prefixes; consumers add prefix of sums[].
__global__ __launch_bounds__(1024) void k_scan_attn(const int* __restrict__ deg,
                                                    int* __restrict__ start,
                                                    int* __restrict__ sums,
                                                    int Ntot, int N, int nscan,
                                                    const float* __restrict__ x,
                                                    const float* __restrict__ w_s,
                                                    const float* __restrict__ w_d,
                                                    float* __restrict__ a_s,
                                                    float* __restrict__ a_d,
                                                    _Float16* __restrict__ xh)
{
    if ((int)blockIdx.x < nscan) {
        __shared__ int sm[1024];
        int tid = threadIdx.x;
        int i = blockIdx.x * 1024 + tid;
        int v = (i < N) ? deg[i] : 0;
        sm[tid] = v; __syncthreads();
        for (int off = 1; off < 1024; off <<= 1) {
            int t = (tid >= off) ? sm[tid - off] : 0;
            __syncthreads();
            sm[tid] += t;
            __syncthreads();
        }
        if (i < Ntot) start[i] = sm[tid] - v;
        if (tid == 1023) sums[blockIdx.x] = sm[1023];
    } else {
        int n = (blockIdx.x - nscan) * 16 + (threadIdx.x >> 6);
        if (n >= N) return;
        int lane = threadIdx.x & 63;
        float2 xv = *(const float2*)(x + (size_t)n * 128 + lane * 2);
        f16x2 hv = { (_Float16)xv.x, (_Float16)xv.y };
        *(f16x2*)(xh + (size_t)n * 128 + lane * 2) = hv;
        float ps[4], pd[4];
        #pragma unroll
        for (int h = 0; h < 4; ++h) {
            float2 sv = *(const float2*)(w_s + h * 128 + lane * 2);
            float2 dv = *(const float2*)(w_d + h * 128 + lane * 2);
            ps[h] = xv.x * sv.x + xv.y * sv.y;
            pd[h] = xv.x * dv.x + xv.y * dv.y;
        }
        #pragma unroll
        for (int h = 0; h < 4; ++h)
            for (int off = 32; off; off >>= 1) {
                ps[h] += __shfl_xor(ps[h], off);
                pd[h] += __shfl_xor(pd[h], off);
            }
        if (lane == 0) {
            *(float4*)(a_s + (size_t)n * 4) = make_float4(ps[0], ps[1], ps[2], ps[3]);
            *(float4*)(a_d + (size_t)n * 4) = make_float4(pd[0], pd[1], pd[2], pd[3]);
        }
    }
}

// ============ CSR fill (adds scan-block prefix from sums[] inline) ============
__global__ __launch_bounds__(256) void k_fill(const int* __restrict__ ei, const int* __restrict__ start,
                                              const unsigned short* __restrict__ rank,
                                              const int* __restrict__ sums, int nscan,
                                              unsigned short* __restrict__ csr_src, int E, int Ep)
{
    __shared__ int pref[64];
    if (threadIdx.x == 0) {
        int a = 0;
        for (int b = 0; b < nscan; ++b) { pref[b] = a; a += sums[b]; }
    }
    __syncthreads();
    int e = blockIdx.x * blockDim.x + threadIdx.x;
    if (e >= Ep) return;
    int src, dst;
    if (e < E) { src = ei[e]; dst = ei[E + e]; } else { src = dst = e - E; }
    csr_src[start[dst] + pref[dst >> 10] + rank[e]] = (unsigned short)src;
}

// ============ FUSED layer-1 + layer-2 projection, hi-only weights (precision probe) ============
// Wlo dropped: halves MFMA, cuts staging 33-50%, LDS 59.4->51.2KB -> 3 blocks/CU.
#define LSG 32    // halfs per staging row (linear, required by global_load_lds)
#define CP  136   // halfs per Ct tile row (128 + 8 pad)
__global__ __launch_bounds__(256, 3) void k_gemm12(
    const _Float16* __restrict__ agg,
    const _Float16* __restrict__ W1hi, const _Float16* __restrict__ W1lo,
    const float* __restrict__ b1,
    const _Float16* __restrict__ W2hi, const _Float16* __restrict__ W2lo,
    _Float16* __restrict__ xh2,
    const float* __restrict__ as2, const float* __restrict__ ad2,
    float* __restrict__ As2, float* __restrict__ Ad2,
    float* __restrict__ pooled, int M)
{
    __shared__ __align__(16) _Float16 smem[128 * LSG * 2 + 128 * CP];
    _Float16* As  = smem;                 // [128][32]
    _Float16* Bhs = smem + 128 * LSG;     // [128][32]
    _Float16* Ct  = smem + 256 * LSG;     // h1 tile / C staging, stride CP

    const int tid = threadIdx.x;
    const int wave = tid >> 6, lane = tid & 63;
    const int wm = wave >> 1, wn = wave & 1;
    const int quad = lane >> 4, l16 = lane & 15;
    const int m0 = blockIdx.x * 128;
    const int crow = lane >> 2, ckq = lane & 3;   // within-chunk row / 8-half group

    f32x4 acc2[4][4] = {};

    for (int h = 0; h < 4; ++h) {
        // ---- stage 1: h1_h tile = agg[:, h*128 +k] @ W1hi_h^T ----
        f32x4 acc1[4][4] = {};
        for (int k0 = 0; k0 < 128; k0 += 32) {
            #pragma unroll
            for (int cc = 0; cc < 2; ++cc) {
                int c = wave * 2 + cc;                 // chunk 0..7 (16 rows, 1KB)
                int row = c * 16 + crow;
                gl_lds16(agg + (size_t)(m0 + row) * 512 + h * 128 + k0 + ckq * 8,
                         As + (size_t)c * 512);
                size_t brow = (size_t)(h * 128 + row) * 128 + k0 + ckq * 8;
                gl_lds16(W1hi + brow, Bhs + (size_t)c * 512);
            }
            __syncthreads();
            f16x8 af[4], bhf[4];
            #pragma unroll
            for (int i = 0; i < 4; ++i) {
                af[i]  = *(const f16x8*)&As [(wm * 64 + i * 16 + l16) * LSG + quad * 8];
                bhf[i] = *(const f16x8*)&Bhs[(wn * 64 + i * 16 + l16) * LSG + quad * 8];
            }
            #pragma unroll
            for (int i = 0; i < 4; ++i)
                #pragma unroll
                for (int j = 0; j < 4; ++j)
                    acc1[i][j] = __builtin_amdgcn_mfma_f32_16x16x32_f16(af[i], bhf[j], acc1[i][j], 0, 0, 0);
            __syncthreads();
        }
        // ---- park h1_h (bias + ELU, fp16 rounding) in LDS ----
        #pragma unroll
        for (int j = 0; j < 4; ++j) {
            int n = wn * 64 + j * 16 + l16;
            float bb = b1[h * 128 + n];
            #pragma unroll
            for (int i = 0; i < 4; ++i)
                #pragma unroll
                for (int r = 0; r < 4; ++r)
                    Ct[(wm * 64 + i * 16 + quad * 4 + r) * CP + n] = (_Float16)elu(acc1[i][j][r] + bb);
        }
        __syncthreads();
        // ---- stage 2: acc2 += h1_h @ W2hi[:, h*128 +k]^T ----
        for (int k0 = 0; k0 < 128; k0 += 32) {
            #pragma unroll
            for (int cc = 0; cc < 2; ++cc) {
                int c = wave * 2 + cc;
                int row = c * 16 + crow;
                size_t brow = (size_t)row * 512 + h * 128 + k0 + ckq * 8;
                gl_lds16(W2hi + brow, Bhs + (size_t)c * 512);
            }
            __syncthreads();
            f16x8 af[4], bhf[4];
            #pragma unroll
            for (int i = 0; i < 4; ++i) {
                af[i]  = *(const f16x8*)&Ct [(wm * 64 + i * 16 + l16) * CP + k0 + quad * 8];
                bhf[i] = *(const f16x8*)&Bhs[(wn * 64 + i * 16 + l16) * LSG + quad * 8];
            }
            #pragma unroll
            for (int i = 0; i < 4; ++i)
                #pragma unroll
                for (int j = 0; j < 4; ++j)
                    acc2[i][j] = __builtin_amdgcn_mfma_f32_16x16x32_f16(af[i], bhf[j], acc2[i][j], 0, 0, 0);
            __syncthreads();
        }
    }

    // ---- epilogue: stage acc2 tile, write xh2, attn2 logits, zero pooled ----
    #pragma unroll
    for (int j = 0; j < 4; ++j) {
        int n = wn * 64 + j * 16 + l16;
        #pragma unroll
        for (int i = 0; i < 4; ++i)
            #pragma unroll
            for (int r = 0; r < 4; ++r)
                Ct[(wm * 64 + i * 16 + quad * 4 + r) * CP + n] = (_Float16)acc2[i][j][r];
    }
    __syncthreads();
    for (int c = tid; c < 2048; c += 256) {
        int row = c >> 4, col8 = (c & 15) * 8;
        int m = m0 + row;
        if (m < M)
            *(f16x8*)(xh2 + (size_t)m * 128 + col8) = *(const f16x8*)&Ct[row * CP + col8];
    }
    {
        int row = tid >> 1, half = tid & 1;
        int d = m0 + row;
        float ss = 0.f, sd = 0.f;
        const _Float16* rp = &Ct[row * CP + half * 64];
        #pragma unroll
        for (int c8 = 0; c8 < 8; ++c8) {
            f16x8 v = *(const f16x8*)(rp + c8 * 8);
            #pragma unroll
            for (int c = 0; c < 8; ++c) {
                float f = (float)v[c];
                int n = half * 64 + c8 * 8 + c;
                ss += f * as2[n];
                sd += f * ad2[n];
            }
        }
        ss += __shfl_xor(ss, 1);
        sd += __shfl_xor(sd, 1);
        if (half == 0 && d < M) { As2[d] = ss; Ad2[d] = sd; }
    }
    // zero pooled (completes before k_gat2 launches)
    for (int i = blockIdx.x * 256 + tid; i < 128 * 128; i += gridDim.x * 256)
        pooled[i] = 0.f;
}

// ============ layer-1 gather: 16-lane group per dst, 8-edge unrolled ============
__global__ __launch_bounds__(256) void k_gat1(const int* __restrict__ start,
                                              const int* __restrict__ sums,
                                              const unsigned short* __restrict__ csr,
                                              const float* __restrict__ a_s,
                                              const float* __restrict__ a_d,
                                              const _Float16* __restrict__ x,
                                              _Float16* __restrict__ agg, int N)
{
    int d = blockIdx.x * 16 + (threadIdx.x >> 4);
    if (d >= N) return;
    int g16 = threadIdx.x & 15;
    int j = d >> 10;
    int p0 = 0;
    for (int b = 0; b < j; ++b) p0 += sums[b];
    int p1 = p0 + ((((d + 1) >> 10) != j) ? sums[j] : 0);
    int beg = start[d] + p0, end = start[d + 1] + p1;
    int deg = end - beg;
    float4 ad4 = *(const float4*)(a_d + (size_t)d * 4);

    float sum0 = 0.f, sum1 = 0.f, sum2 = 0.f, sum3 = 0.f;
    f32x2 acc[4][4] = {};
    const _Float16* xb = x + g16 * 8;

    for (int base = 0; base < deg; base += 16) {
        int nch = deg - base; if (nch > 16) nch = 16;
        int s = 0;
        float e0 = 0.f, e1 = 0.f, e2 = 0.f, e3 = 0.f;
        if (g16 < nch) {
            s = csr[beg + base + g16];
            float4 as4 = *(const float4*)(a_s + (size_t)s * 4);
            e0 = __expf(leaky(as4.x + ad4.x));
            e1 = __expf(leaky(as4.y + ad4.y));
            e2 = __expf(leaky(as4.z + ad4.z));
            e3 = __expf(leaky(as4.w + ad4.w));
            sum0 += e0; sum1 += e1; sum2 += e2; sum3 += e3;
        }
        int t = 0;
        for (; t + 8 <= nch; t += 8) {
            int si[8];
            #pragma unroll
            for (int u = 0; u < 8; ++u) si[u] = __shfl(s, t + u, 16);
            f16x8 hv[8];
            #pragma unroll
            for (int u = 0; u < 8; ++u) hv[u] = *(const f16x8*)(xb + (size_t)si[u] * 128);
            #pragma unroll
            for (int u = 0; u < 8; ++u) {
                float w0 = __shfl(e0, t + u, 16), w1 = __shfl(e1, t + u, 16);
                float w2 = __shfl(e2, t + u, 16), w3 = __shfl(e3, t + u, 16);
                #pragma unroll
                for (int p = 0; p < 4; ++p) {
                    f32x2 v = { (float)hv[u][2*p], (float)hv[u][2*p+1] };
                    acc[0][p] += w0 * v;
                    acc[1][p] += w1 * v;
                    acc[2][p] += w2 * v;
                    acc[3][p] += w3 * v;
                }
            }
        }
        for (; t + 4 <= nch; t += 4) {
            int sA = __shfl(s, t, 16),     sB = __shfl(s, t + 1, 16);
            int sC = __shfl(s, t + 2, 16), sD = __shfl(s, t + 3, 16);
            f16x8 hA = *(const f16x8*)(xb + (size_t)sA * 128);
            f16x8 hB = *(const f16x8*)(xb + (size_t)sB * 128);
            f16x8 hC = *(const f16x8*)(xb + (size_t)sC * 128);
            f16x8 hD = *(const f16x8*)(xb + (size_t)sD * 128);
            float w0A = __shfl(e0, t, 16),     w1A = __shfl(e1, t, 16);
            float w2A = __shfl(e2, t, 16),     w3A = __shfl(e3, t, 16);
            float w0B = __shfl(e0, t + 1, 16), w1B = __shfl(e1, t + 1, 16);
            float w2B = __shfl(e2, t + 1, 16), w3B = __shfl(e3, t + 1, 16);
            float w0C = __shfl(e0, t + 2, 16), w1C = __shfl(e1, t + 2, 16);
            float w2C = __shfl(e2, t + 2, 16), w3C = __shfl(e3, t + 2, 16);
            float w0D = __shfl(e0, t + 3, 16), w1D = __shfl(e1, t + 3, 16);
            float w2D = __shfl(e2, t + 3, 16), w3D = __shfl(e3, t + 3, 16);
            #pragma unroll
            for (int p = 0; p < 4; ++p) {
                f32x2 vA = { (float)hA[2*p], (float)hA[2*p+1] };
                f32x2 vB = { (float)hB[2*p], (float)hB[2*p+1] };
                f32x2 vC = { (float)hC[2*p], (float)hC[2*p+1] };
                f32x2 vD = { (float)hD[2*p], (float)hD[2*p+1] };
                acc[0][p] += w0A * vA + w0B * vB + w0C * vC + w0D * vD;
                acc[1][p] += w1A * vA + w1B * vB + w1C * vC + w1D * vD;
                acc[2][p] += w2A * vA + w2B * vB + w2C * vC + w2D * vD;
                acc[3][p] += w3A * vA + w3B * vB + w3C * vC + w3D * vD;
            }
        }
        for (; t < nch; ++t) {
            int   si = __shfl(s,  t, 16);
            float w0 = __shfl(e0, t, 16);
            float w1 = __shfl(e1, t, 16);
            float w2 = __shfl(e2, t, 16);
            float w3 = __shfl(e3, t, 16);
            f16x8 hv = *(const f16x8*)(xb + (size_t)si * 128);
            #pragma unroll
            for (int p = 0; p < 4; ++p) {
                f32x2 v = { (float)hv[2*p], (float)hv[2*p+1] };
                acc[0][p] += w0 * v;
                acc[1][p] += w1 * v;
                acc[2][p] += w2 * v;
                acc[3][p] += w3 * v;
            }
        }
    }
    #pragma unroll
    for (int o = 1; o < 16; o <<= 1) {
        sum0 += __shfl_xor(sum0, o, 16); sum1 += __shfl_xor(sum1, o, 16);
        sum2 += __shfl_xor(sum2, o, 16); sum3 += __shfl_xor(sum3, o, 16);
    }
    float inv[4] = { 1.f / (sum0 + 1e-16f), 1.f / (sum1 + 1e-16f),
                     1.f / (sum2 + 1e-16f), 1.f / (sum3 + 1e-16f) };
    _Float16* o = agg + (size_t)d * 512 + g16 * 8;
    #pragma unroll
    for (int h = 0; h < 4; ++h) {
        f16x8 ov;
        #pragma unroll
        for (int p = 0; p < 4; ++p) {
            ov[2 * p]     = (_Float16)(acc[h][p].x * inv[h]);
            ov[2 * p + 1] = (_Float16)(acc[h][p].y * inv[h]);
        }
        *(f16x8*)(o + h * 128) = ov;
    }
}

// ============ layer-2 gather + bias + ELU, FUSED mean-pool via block LDS reduction ============
__global__ __launch_bounds__(256) void k_gat2(const int* __restrict__ start,
                                              const int* __restrict__ sums,
                                              const unsigned short* __restrict__ csr,
                                              const float* __restrict__ a_s,
                                              const float* __restrict__ a_d,
                                              const _Float16* __restrict__ xh2,
                                              const float* __restrict__ b2,
                                              const int* __restrict__ batch,
                                              float* __restrict__ pooled, int N)
{
    __shared__ float sm[16][128];
    __shared__ int sbat[16];
    const int grp = threadIdx.x >> 4;
    const int g16 = threadIdx.x & 15;
    const int d = blockIdx.x * 16 + grp;

    float vals[8];
    #pragma unroll
    for (int j = 0; j < 8; ++j) vals[j] = 0.f;

    if (d < N) {
        int jb = d >> 10;
        int p0 = 0;
        for (int b = 0; b < jb; ++b) p0 += sums[b];
        int p1 = p0 + ((((d + 1) >> 10) != jb) ? sums[jb] : 0);
        int beg = start[d] + p0, end = start[d + 1] + p1;
        int deg = end - beg;
        float ad = a_d[d];
        float sum = 0.f;
        f32x2 acc[4] = {};
        const _Float16* xb = xh2 + g16 * 8;

        for (int base = 0; base < deg; base += 16) {
            int nch = deg - base; if (nch > 16) nch = 16;
            int s = 0; float e = 0.f;
            if (g16 < nch) {
                s = csr[beg + base + g16];
                e = __expf(leaky(a_s[s] + ad));
                sum += e;
            }
            int t = 0;
            for (; t + 8 <= nch; t += 8) {
                int si[8];
                #pragma unroll
                for (int u = 0; u < 8; ++u) si[u] = __shfl(s, t + u, 16);
                f16x8 hv[8];
                #pragma unroll
                for (int u = 0; u < 8; ++u) hv[u] = *(const f16x8*)(xb + (size_t)si[u] * 128);
                #pragma unroll
                for (int u = 0; u < 8; ++u) {
                    float w = __shfl(e, t + u, 16);
                    #pragma unroll
                    for (int p = 0; p < 4; ++p) {
                        f32x2 v = { (float)hv[u][2*p], (float)hv[u][2*p+1] };
                        acc[p] += w * v;
                    }
                }
            }
            for (; t + 4 <= nch; t += 4) {
                int sA = __shfl(s, t, 16),     sB = __shfl(s, t + 1, 16);
                int sC = __shfl(s, t + 2, 16), sD = __shfl(s, t + 3, 16);
                f16x8 hA = *(const f16x8*)(xb + (size_t)sA * 128);
                f16x8 hB = *(const f16x8*)(xb + (size_t)sB * 128);
                f16x8 hC = *(const f16x8*)(xb + (size_t)sC * 128);
                f16x8 hD = *(const f16x8*)(xb + (size_t)sD * 128);
                float wA = __shfl(e, t, 16),     wB = __shfl(e, t + 1, 16);
                float wC = __shfl(e, t + 2, 16), wD = __shfl(e, t + 3, 16);
                #pragma unroll
                for (int p = 0; p < 4; ++p) {
                    f32x2 vA = { (float)hA[2*p], (float)hA[2*p+1] };
                    f32x2 vB = { (float)hB[2*p], (float)hB[2*p+1] };
                    f32x2 vC = { (float)hC[2*p], (float)hC[2*p+1] };
                    f32x2 vD = { (float)hD[2*p], (float)hD[2*p+1] };
                    acc[p] += wA * vA + wB * vB + wC * vC + wD * vD;
                }
            }
            for (; t < nch; ++t) {
                int   si = __shfl(s, t, 16);
                float w  = __shfl(e, t, 16);
                f16x8 hv = *(const f16x8*)(xb + (size_t)si * 128);
                #pragma unroll
                for (int p = 0; p < 4; ++p) {
                    f32x2 v = { (float)hv[2*p], (float)hv[2*p+1] };
                    acc[p] += w * v;
                }
            }
        }
        #pragma unroll
        for (int o = 1; o < 16; o <<= 1) sum += __shfl_xor(sum, o, 16);
        float inv = 1.f / (sum + 1e-16f);
        #pragma unroll
        for (int p = 0; p < 4; ++p) {
            vals[2 * p]     = elu(acc[p].x * inv + b2[g16 * 8 + 2 * p]);
            vals[2 * p + 1] = elu(acc[p].y * inv + b2[g16 * 8 + 2 * p + 1]);
        }
        if (g16 == 0) sbat[grp] = batch[d];
    } else {
        if (g16 == 0) sbat[grp] = -1;
    }
    #pragma unroll
    for (int j = 0; j < 8; ++j) sm[grp][g16 * 8 + j] = vals[j];
    __syncthreads();

    // 128 threads run the poolA run-length logic over the 16 staged rows
    if (threadIdx.x < 128) {
        int c = threadIdx.x;
        float acc = 0.f;
        int g = sbat[0];
        #pragma unroll
        for (int r = 0; r < 16; ++r) {
            int bg = sbat[r];
            if (bg < 0) break;
            if (bg != g) { atomicAdd(&pooled[(size_t)g * 128 + c], acc); acc = 0.f; g = bg; }
            acc += sm[r][c];
        }
        atomicAdd(&pooled[(size_t)g * 128 + c], acc);
    }
}

// ============ head: mean + relu(pooled@Wh1^T+bh1) @ Wh2^T + bh2 ============
__global__ __launch_bounds__(128) void k_head(const float* __restrict__ pooled,
                                              const int* __restrict__ gstart,
                                              const float* __restrict__ Wh1,
                                              const float* __restrict__ bh1,
                                              const float* __restrict__ Wh2,
                                              const float* __restrict__ bh2,
                                              float* __restrict__ out)
{
    int g = blockIdx.x, c = threadIdx.x;
    __shared__ float p[128];
    __shared__ float red[128];
    float cf = (float)(gstart[g + 1] - gstart[g]); cf = cf > 1.f ? cf : 1.f;
    p[c] = pooled[(size_t)g * 128 + c] / cf;
    __syncthreads();
    float z = bh1[c];
    for (int k = 0; k < 128; ++k) z += p[k] * Wh1[c * 128 + k];
    z = z > 0.f ? z : 0.f;
    red[c] = z * Wh2[c];
    __syncthreads();
    for (int st = 64; st > 0; st >>= 1) { if (c < st) red[c] += red[c + st]; __syncthreads(); }
    if (c == 0) out[g] = red[0] + bh2[0];
}

// ============ launch ============
extern "C" void kernel_launch(void* const* d_in, const int* in_sizes, int n_in,
                              void* d_out, int out_size, void* d_ws, size_t ws_size,
                              hipStream_t stream)
{
    const float* x   = (const float*)d_in[0];
    const int*   ei  = (const int*)d_in[1];
    const int*   bat = (const int*)d_in[2];
    const float* W1  = (const float*)d_in[3];
    const float* as1 = (const float*)d_in[4];
    const float* ad1 = (const float*)d_in[5];
    const float* b1  = (const float*)d_in[6];
    const float* W2  = (const float*)d_in[7];
    const float* as2 = (const float*)d_in[8];
    const float* ad2 = (const float*)d_in[9];
    const float* b2  = (const float*)d_in[10];
    const float* Wh1 = (const float*)d_in[11];
    const float* bh1 = (const float*)d_in[12];
    const float* Wh2 = (const float*)d_in[13];
    const float* bh2 = (const float*)d_in[14];
    float* out = (float*)d_out;

    const int N  = in_sizes[0] / 128;
    const int E  = in_sizes[1] / 2;
    const int Ep = E + N;
    const int G  = 128;
    const int nscan = (N + 1 + 1023) / 1024;

    char* w = (char*)d_ws;
    size_t off = 0;
    auto alloc = [&](size_t bytes) -> char* {
        char* p = w + off; off += (bytes + 511) & ~(size_t)511; return p;
    };
    _Float16* x_h  = (_Float16*)alloc((size_t)N * 128 * 2);
    _Float16* agg  = (_Float16*)alloc((size_t)N * 512 * 2);
    _Float16* xh2h = (_Float16*)alloc((size_t)N * 128 * 2);
    float*    As1  = (float*)alloc((size_t)N * 4 * 4);
    float*    Ad1  = (float*)alloc((size_t)N * 4 * 4);
    float*    As2  = (float*)alloc((size_t)N * 4);
    float*    Ad2  = (float*)alloc((size_t)N * 4);
    _Float16* W1hi = (_Float16*)alloc(65536 * 2);
    _Float16* W1lo = (_Float16*)alloc(65536 * 2);
    _Float16* W2hi = (_Float16*)alloc(65536 * 2);
    _Float16* W2lo = (_Float16*)alloc(65536 * 2);
    int* startb = (int*)alloc((size_t)(N + 1) * 4);
    unsigned short* csr  = (unsigned short*)alloc((size_t)Ep * 2);
    unsigned short* rank = (unsigned short*)alloc((size_t)Ep * 2);
    int* sums   = (int*)alloc(4096);
    int* gstart = (int*)alloc((size_t)(G + 1) * 4);
    float* pooled = (float*)alloc((size_t)G * 128 * 4);   // zeroed by k_gemm12 epilogue
    char* zbase = w + off;                                // zero-init group (deg, w_s1, w_d1)
    int*   deg    = (int*)alloc((size_t)N * 4);
    float* w_s1 = (float*)alloc(512 * 4);
    float* w_d1 = (float*)alloc(512 * 4);
    size_t zbytes = (size_t)((w + off) - zbase);

    hipMemsetAsync(zbase, 0, zbytes, stream);

    // 1) fused: weight split + parallel attn fold (atomic) + CSR degree count + graph boundaries
    int nbc = (Ep + 255) / 256, nbg = (N + 255) / 256;
    k_front<<<576 + nbc + nbg, 256, 0, stream>>>(W1, W2, as1, ad1, W1hi, W1lo, W2hi, W2lo,
                                                 w_s1, w_d1, ei, deg, rank, bat, gstart,
                                                 E, Ep, N, G, nbc);
    // 2) fused: degree scan (block-local) || layer-1 logits + fp16 x
    k_scan_attn<<<nscan + (N + 15) / 16, 1024, 0, stream>>>(deg, startb, sums, N + 1, N, nscan,
                                                            x, w_s1, w_d1, As1, Ad1, x_h);
    // 3) CSR fill (adds block prefix inline)
    k_fill<<<(Ep + 255) / 256, 256, 0, stream>>>(ei, startb, rank, sums, nscan, csr, E, Ep);
    // 4) layer-1 gather -> agg fp16 [N, 4*128]
    k_gat1<<<(N + 15) / 16, 256, 0, stream>>>(startb, sums, csr, As1, Ad1, x_h, agg, N);
    // 5) FUSED: h1 = ELU(blockdiag proj + b1) [LDS only] ; xh2 = h1 @ W2^T ; attn2 logits ; zero pooled
    k_gemm12<<<(N + 127) / 128, 256, 0, stream>>>(agg, W1hi, W1lo, b1, W2hi, W2lo,
                                                  xh2h, as2, ad2, As2, Ad2, pooled, N);
    // 6) layer-2 gather + bias + ELU + fused mean-pool (block LDS reduction, few atomics)
    k_gat2<<<(N + 15) / 16, 256, 0, stream>>>(startb, sums, csr, As2, Ad2, xh2h, b2, bat, pooled, N);
    // 7) MLP head
    k_head<<<G, 128, 0, stream>>>(pooled, gstart, Wh1, bh1, Wh2, bh2, out);
}

// Round 16
// 299.327 us; speedup vs baseline: 1.0545x; 1.0545x over previous
//
#include <hip/hip_runtime.h>
#include <cstdint>
#include <cstddef>

#define NEG_SLOPE 0.2f

typedef _Float16 f16x8 __attribute__((ext_vector_type(8)));
typedef _Float16 f16x2 __attribute__((ext_vector_type(2)));
typedef float    f32x4 __attribute__((ext_vector_type(4)));
typedef float    f32x2 __attribute__((ext_vector_type(2)));

__device__ __forceinline__ float leaky(float x){ return x > 0.f ? x : NEG_SLOPE * x; }
__device__ __forceinline__ float elu(float x){ return x > 0.f ? x : __expf(x) - 1.f; }

// async global->LDS, 16B per lane (lds base must be wave-uniform; HW writes base + lane*16)
__device__ __forceinline__ void gl_lds16(const void* g, void* l) {
    __builtin_amdgcn_global_load_lds((const __attribute__((address_space(1))) unsigned int*)g,
                                     (__attribute__((address_space(3))) unsigned int*)l, 16, 0, 0);
}

// ============ front: weight split + parallel attn fold + CSR count + graph bounds ============
__global__ __launch_bounds__(256) void k_front(const float* __restrict__ W1,
                                               const float* __restrict__ W2,
                                               const float* __restrict__ as1,
                                               const float* __restrict__ ad1,
                                               _Float16* __restrict__ W1hi, _Float16* __restrict__ W1lo,
                                               _Float16* __restrict__ W2hi, _Float16* __restrict__ W2lo,
                                               float* __restrict__ w_s, float* __restrict__ w_d,
                                               const int* __restrict__ ei, int* __restrict__ deg,
                                               unsigned short* __restrict__ rank,
                                               const int* __restrict__ batch, int* __restrict__ gstart,
                                               int E, int Ep, int N, int G, int nbc)
{
    int b = blockIdx.x;
    if (b < 512) {
        const float* src = (b < 256) ? W1 : W2;
        _Float16* hi = (b < 256) ? W1hi : W2hi;
        _Float16* lo = (b < 256) ? W1lo : W2lo;
        int i = ((b & 255) << 8) + threadIdx.x;
        float v = src[i];
        _Float16 h = (_Float16)v;
        hi[i] = h;
        lo[i] = (_Float16)(v - (float)h);
    } else if (b < 576) {
        // attn fold, c-parallel: block covers (h, 8 c-values); w_s/w_d are pre-zeroed.
        int b2 = b - 512;
        int h  = b2 >> 4;           // 0..3
        int cg = b2 & 15;           // 0..15 -> c in [cg*8, cg*8+8)
        int k  = threadIdx.x & 127;
        int c0 = cg * 8 + (threadIdx.x >> 7) * 4;
        float s = 0.f, d = 0.f;
        #pragma unroll
        for (int cc = 0; cc < 4; ++cc) {
            int c = c0 + cc;
            float w = W1[((size_t)(h * 128 + c)) * 128 + k];
            s += as1[h * 128 + c] * w;
            d += ad1[h * 128 + c] * w;
        }
        atomicAdd(&w_s[h * 128 + k], s);
        atomicAdd(&w_d[h * 128 + k], d);
    } else if (b < 576 + nbc) {
        int e = (b - 576) * 256 + threadIdx.x;
        if (e >= Ep) return;
        int dst = (e < E) ? ei[E + e] : (e - E);
        rank[e] = (unsigned short)atomicAdd(&deg[dst], 1);
    } else {
        int n = (b - 576 - nbc) * 256 + threadIdx.x;
        if (n >= N) return;
        int bb = batch[n];
        int prev = (n == 0) ? -1 : batch[n - 1];
        for (int g = prev + 1; g <= bb; ++g) gstart[g] = n;
        if (n == N - 1)
            for (int g = bb + 1; g <= G; ++g) gstart[g] = N;
    }
}

// ============ scanA (block-local scan of degrees) || layer-1 attn logits + fp16 x ============
// start[] holds BLOCK-LOCAL exclusive prefixes; consumers add prefix of sums[].
__global__ __launch_bounds__(1024) void k_scan_attn(const int* __restrict__ deg,
                                                    int* __restrict__ start,
                                                    int* __restrict__ sums,
                                                    int Ntot, int N, int nscan,
                                                    const float* __restrict__ x,
                                                    const float* __restrict__ w_s,
                                                    const float* __restrict__ w_d,
                                                    float* __restrict__ a_s,
                                                    float* __restrict__ a_d,
                                                    _Float16* __restrict__ xh)
{
    if ((int)blockIdx.x < nscan) {
        __shared__ int sm[1024];
        int tid = threadIdx.x;
        int i = blockIdx.x * 1024 + tid;
        int v = (i < N) ? deg[i] : 0;
        sm[tid] = v; __syncthreads();
        for (int off = 1; off < 1024; off <<= 1) {
            int t = (tid >= off) ? sm[tid - off] : 0;
            __syncthreads();
            sm[tid] += t;
            __syncthreads();
        }
        if (i < Ntot) start[i] = sm[tid] - v;
        if (tid == 1023) sums[blockIdx.x] = sm[1023];
    } else {
        int n = (blockIdx.x - nscan) * 16 + (threadIdx.x >> 6);
        if (n >= N) return;
        int lane = threadIdx.x & 63;
        float2 xv = *(const float2*)(x + (size_t)n * 128 + lane * 2);
        f16x2 hv = { (_Float16)xv.x, (_Float16)xv.y };
        *(f16x2*)(xh + (size_t)n * 128 + lane * 2) = hv;
        float ps[4], pd[4];
        #pragma unroll
        for (int h = 0; h < 4; ++h) {
            float2 sv = *(const float2*)(w_s + h * 128 + lane * 2);
            float2 dv = *(const float2*)(w_d + h * 128 + lane * 2);
            ps[h] = xv.x * sv.x + xv.y * sv.y;
            pd[h] = xv.x * dv.x + xv.y * dv.y;
        }
        #pragma unroll
        for (int h = 0; h < 4; ++h)
            for (int off = 32; off; off >>= 1) {
                ps[h] += __shfl_xor(ps[h], off);
                pd[h] += __shfl_xor(pd[h], off);
            }
        if (lane == 0) {
            *(float4*)(a_s + (size_t)n * 4) = make_float4(ps[0], ps[1], ps[2], ps[3]);
            *(float4*)(a_d + (size_t)n * 4) = make_float4(pd[0], pd[1], pd[2], pd[3]);
        }
    }
}

// ============ CSR fill (adds scan-block prefix from sums[] inline) ============
__global__ __launch_bounds__(256) void k_fill(const int* __restrict__ ei, const int* __restrict__ start,
                                              const unsigned short* __restrict__ rank,
                                              const int* __restrict__ sums, int nscan,
                                              unsigned short* __restrict__ csr_src, int E, int Ep)
{
    __shared__ int pref[64];
    if (threadIdx.x == 0) {
        int a = 0;
        for (int b = 0; b < nscan; ++b) { pref[b] = a; a += sums[b]; }
    }
    __syncthreads();
    int e = blockIdx.x * blockDim.x + threadIdx.x;
    if (e >= Ep) return;
    int src, dst;
    if (e < E) { src = ei[e]; dst = ei[E + e]; } else { src = dst = e - E; }
    csr_src[start[dst] + pref[dst >> 10] + rank[e]] = (unsigned short)src;
}

// ============ FUSED layer-1 + layer-2 projection, hi-only weights, natural occupancy ============
// (256,2): do NOT demand 3 blocks/CU -- round 15 showed that caps VGPR at 84 and spills
// the 128-reg accumulator state to scratch (WRITE_SIZE 13->52 MB). With hi-only weights the
// natural allocation is ~100-110 VGPR; HW reaches 3 blocks/CU on its own (LDS 51.2KB*3<160KB).
#define LSG 32    // halfs per staging row (linear, required by global_load_lds)
#define CP  136   // halfs per Ct tile row (128 + 8 pad)
__global__ __launch_bounds__(256, 2) void k_gemm12(
    const _Float16* __restrict__ agg,
    const _Float16* __restrict__ W1hi, const _Float16* __restrict__ W1lo,
    const float* __restrict__ b1,
    const _Float16* __restrict__ W2hi, const _Float16* __restrict__ W2lo,
    _Float16* __restrict__ xh2,
    const float* __restrict__ as2, const float* __restrict__ ad2,
    float* __restrict__ As2, float* __restrict__ Ad2,
    float* __restrict__ pooled, int M)
{
    __shared__ __align__(16) _Float16 smem[128 * LSG * 2 + 128 * CP];
    _Float16* As  = smem;                 // [128][32]
    _Float16* Bhs = smem + 128 * LSG;     // [128][32]
    _Float16* Ct  = smem + 256 * LSG;     // h1 tile / C staging, stride CP

    const int tid = threadIdx.x;
    const int wave = tid >> 6, lane = tid & 63;
    const int wm = wave >> 1, wn = wave & 1;
    const int quad = lane >> 4, l16 = lane & 15;
    const int m0 = blockIdx.x * 128;
    const int crow = lane >> 2, ckq = lane & 3;   // within-chunk row / 8-half group

    f32x4 acc2[4][4] = {};

    for (int h = 0; h < 4; ++h) {
        // ---- stage 1: h1_h tile = agg[:, h*128 +k] @ W1hi_h^T ----
        f32x4 acc1[4][4] = {};
        for (int k0 = 0; k0 < 128; k0 += 32) {
            #pragma unroll
            for (int cc = 0; cc < 2; ++cc) {
                int c = wave * 2 + cc;                 // chunk 0..7 (16 rows, 1KB)
                int row = c * 16 + crow;
                gl_lds16(agg + (size_t)(m0 + row) * 512 + h * 128 + k0 + ckq * 8,
                         As + (size_t)c * 512);
                size_t brow = (size_t)(h * 128 + row) * 128 + k0 + ckq * 8;
                gl_lds16(W1hi + brow, Bhs + (size_t)c * 512);
            }
            __syncthreads();
            f16x8 af[4], bhf[4];
            #pragma unroll
            for (int i = 0; i < 4; ++i) {
                af[i]  = *(const f16x8*)&As [(wm * 64 + i * 16 + l16) * LSG + quad * 8];
                bhf[i] = *(const f16x8*)&Bhs[(wn * 64 + i * 16 + l16) * LSG + quad * 8];
            }
            #pragma unroll
            for (int i = 0; i < 4; ++i)
                #pragma unroll
                for (int j = 0; j < 4; ++j)
                    acc1[i][j] = __builtin_amdgcn_mfma_f32_16x16x32_f16(af[i], bhf[j], acc1[i][j], 0, 0, 0);
            __syncthreads();
        }
        // ---- park h1_h (bias + ELU, fp16 rounding) in LDS ----
        #pragma unroll
        for (int j = 0; j < 4; ++j) {
            int n = wn * 64 + j * 16 + l16;
            float bb = b1[h * 128 + n];
            #pragma unroll
            for (int i = 0; i < 4; ++i)
                #pragma unroll
                for (int r = 0; r < 4; ++r)
                    Ct[(wm * 64 + i * 16 + quad * 4 + r) * CP + n] = (_Float16)elu(acc1[i][j][r] + bb);
        }
        __syncthreads();
        // ---- stage 2: acc2 += h1_h @ W2hi[:, h*128 +k]^T ----
        for (int k0 = 0; k0 < 128; k0 += 32) {
            #pragma unroll
            for (int cc = 0; cc < 2; ++cc) {
                int c = wave * 2 + cc;
                int row = c * 16 + crow;
                size_t brow = (size_t)row * 512 + h * 128 + k0 + ckq * 8;
                gl_lds16(W2hi + brow, Bhs + (size_t)c * 512);
            }
            __syncthreads();
            f16x8 af[4], bhf[4];
            #pragma unroll
            for (int i = 0; i < 4; ++i) {
                af[i]  = *(const f16x8*)&Ct [(wm * 64 + i * 16 + l16) * CP + k0 + quad * 8];
                bhf[i] = *(const f16x8*)&Bhs[(wn * 64 + i * 16 + l16) * LSG + quad * 8];
            }
            #pragma unroll
            for (int i = 0; i < 4; ++i)
                #pragma unroll
                for (int j = 0; j < 4; ++j)
                    acc2[i][j] = __builtin_amdgcn_mfma_f32_16x16x32_f16(af[i], bhf[j], acc2[i][j], 0, 0, 0);
            __syncthreads();
        }
    }

    // ---- epilogue: stage acc2 tile, write xh2, attn2 logits, zero pooled ----
    #pragma unroll
    for (int j = 0; j < 4; ++j) {
        int n = wn * 64 + j * 16 + l16;
        #pragma unroll
        for (int i = 0; i < 4; ++i)
            #pragma unroll
            for (int r = 0; r < 4; ++r)
                Ct[(wm * 64 + i * 16 + quad * 4 + r) * CP + n] = (_Float16)acc2[i][j][r];
    }
    __syncthreads();
    for (int c = tid; c < 2048; c += 256) {
        int row = c >> 4, col8 = (c & 15) * 8;
        int m = m0 + row;
        if (m < M)
            *(f16x8*)(xh2 + (size_t)m * 128 + col8) = *(const f16x8*)&Ct[row * CP + col8];
    }
    {
        int row = tid >> 1, half = tid & 1;
        int d = m0 + row;
        float ss = 0.f, sd = 0.f;
        const _Float16* rp = &Ct[row * CP + half * 64];
        #pragma unroll
        for (int c8 = 0; c8 < 8; ++c8) {
            f16x8 v = *(const f16x8*)(rp + c8 * 8);
            #pragma unroll
            for (int c = 0; c < 8; ++c) {
                float f = (float)v[c];
                int n = half * 64 + c8 * 8 + c;
                ss += f * as2[n];
                sd += f * ad2[n];
            }
        }
        ss += __shfl_xor(ss, 1);
        sd += __shfl_xor(sd, 1);
        if (half == 0 && d < M) { As2[d] = ss; Ad2[d] = sd; }
    }
    // zero pooled (completes before k_gat2 launches)
    for (int i = blockIdx.x * 256 + tid; i < 128 * 128; i += gridDim.x * 256)
        pooled[i] = 0.f;
}

// ============ layer-1 gather: 16-lane group per dst, 8-edge unrolled ============
__global__ __launch_bounds__(256) void k_gat1(const int* __restrict__ start,
                                              const int* __restrict__ sums,
                                              const unsigned short* __restrict__ csr,
                                              const float* __restrict__ a_s,
                                              const float* __restrict__ a_d,
                                              const _Float16* __restrict__ x,
                                              _Float16* __restrict__ agg, int N)
{
    int d = blockIdx.x * 16 + (threadIdx.x >> 4);
    if (d >= N) return;
    int g16 = threadIdx.x & 15;
    int j = d >> 10;
    int p0 = 0;
    for (int b = 0; b < j; ++b) p0 += sums[b];
    int p1 = p0 + ((((d + 1) >> 10) != j) ? sums[j] : 0);
    int beg = start[d] + p0, end = start[d + 1] + p1;
    int deg = end - beg;
    float4 ad4 = *(const float4*)(a_d + (size_t)d * 4);

    float sum0 = 0.f, sum1 = 0.f, sum2 = 0.f, sum3 = 0.f;
    f32x2 acc[4][4] = {};
    const _Float16* xb = x + g16 * 8;

    for (int base = 0; base < deg; base += 16) {
        int nch = deg - base; if (nch > 16) nch = 16;
        int s = 0;
        float e0 = 0.f, e1 = 0.f, e2 = 0.f, e3 = 0.f;
        if (g16 < nch) {
            s = csr[beg + base + g16];
            float4 as4 = *(const float4*)(a_s + (size_t)s * 4);
            e0 = __expf(leaky(as4.x + ad4.x));
            e1 = __expf(leaky(as4.y + ad4.y));
            e2 = __expf(leaky(as4.z + ad4.z));
            e3 = __expf(leaky(as4.w + ad4.w));
            sum0 += e0; sum1 += e1; sum2 += e2; sum3 += e3;
        }
        int t = 0;
        for (; t + 8 <= nch; t += 8) {
            int si[8];
            #pragma unroll
            for (int u = 0; u < 8; ++u) si[u] = __shfl(s, t + u, 16);
            f16x8 hv[8];
            #pragma unroll
            for (int u = 0; u < 8; ++u) hv[u] = *(const f16x8*)(xb + (size_t)si[u] * 128);
            #pragma unroll
            for (int u = 0; u < 8; ++u) {
                float w0 = __shfl(e0, t + u, 16), w1 = __shfl(e1, t + u, 16);
                float w2 = __shfl(e2, t + u, 16), w3 = __shfl(e3, t + u, 16);
                #pragma unroll
                for (int p = 0; p < 4; ++p) {
                    f32x2 v = { (float)hv[u][2*p], (float)hv[u][2*p+1] };
                    acc[0][p] += w0 * v;
                    acc[1][p] += w1 * v;
                    acc[2][p] += w2 * v;
                    acc[3][p] += w3 * v;
                }
            }
        }
        for (; t + 4 <= nch; t += 4) {
            int sA = __shfl(s, t, 16),     sB = __shfl(s, t + 1, 16);
            int sC = __shfl(s, t + 2, 16), sD = __shfl(s, t + 3, 16);
            f16x8 hA = *(const f16x8*)(xb + (size_t)sA * 128);
            f16x8 hB = *(const f16x8*)(xb + (size_t)sB * 128);
            f16x8 hC = *(const f16x8*)(xb + (size_t)sC * 128);
            f16x8 hD = *(const f16x8*)(xb + (size_t)sD * 128);
            float w0A = __shfl(e0, t, 16),     w1A = __shfl(e1, t, 16);
            float w2A = __shfl(e2, t, 16),     w3A = __shfl(e3, t, 16);
            float w0B = __shfl(e0, t + 1, 16), w1B = __shfl(e1, t + 1, 16);
            float w2B = __shfl(e2, t + 1, 16), w3B = __shfl(e3, t + 1, 16);
            float w0C = __shfl(e0, t + 2, 16), w1C = __shfl(e1, t + 2, 16);
            float w2C = __shfl(e2, t + 2, 16), w3C = __shfl(e3, t + 2, 16);
            float w0D = __shfl(e0, t + 3, 16), w1D = __shfl(e1, t + 3, 16);
            float w2D = __shfl(e2, t + 3, 16), w3D = __shfl(e3, t + 3, 16);
            #pragma unroll
            for (int p = 0; p < 4; ++p) {
                f32x2 vA = { (float)hA[2*p], (float)hA[2*p+1] };
                f32x2 vB = { (float)hB[2*p], (float)hB[2*p+1] };
                f32x2 vC = { (float)hC[2*p], (float)hC[2*p+1] };
                f32x2 vD = { (float)hD[2*p], (float)hD[2*p+1] };
                acc[0][p] += w0A * vA + w0B * vB + w0C * vC + w0D * vD;
                acc[1][p] += w1A * vA + w1B * vB + w1C * vC + w1D * vD;
                acc[2][p] += w2A * vA + w2B * vB + w2C * vC + w2D * vD;
                acc[3][p] += w3A * vA + w3B * vB + w3C * vC + w3D * vD;
            }
        }
        for (; t < nch; ++t) {
            int   si = __shfl(s,  t, 16);
            float w0 = __shfl(e0, t, 16);
            float w1 = __shfl(e1, t, 16);
            float w2 = __shfl(e2, t, 16);
            float w3 = __shfl(e3, t, 16);
            f16x8 hv = *(const f16x8*)(xb + (size_t)si * 128);
            #pragma unroll
            for (int p = 0; p < 4; ++p) {
                f32x2 v = { (float)hv[2*p], (float)hv[2*p+1] };
                acc[0][p] += w0 * v;
                acc[1][p] += w1 * v;
                acc[2][p] += w2 * v;
                acc[3][p] += w3 * v;
            }
        }
    }
    #pragma unroll
    for (int o = 1; o < 16; o <<= 1) {
        sum0 += __shfl_xor(sum0, o, 16); sum1 += __shfl_xor(sum1, o, 16);
        sum2 += __shfl_xor(sum2, o, 16); sum3 += __shfl_xor(sum3, o, 16);
    }
    float inv[4] = { 1.f / (sum0 + 1e-16f), 1.f / (sum1 + 1e-16f),
                     1.f / (sum2 + 1e-16f), 1.f / (sum3 + 1e-16f) };
    _Float16* o = agg + (size_t)d * 512 + g16 * 8;
    #pragma unroll
    for (int h = 0; h < 4; ++h) {
        f16x8 ov;
        #pragma unroll
        for (int p = 0; p < 4; ++p) {
            ov[2 * p]     = (_Float16)(acc[h][p].x * inv[h]);
            ov[2 * p + 1] = (_Float16)(acc[h][p].y * inv[h]);
        }
        *(f16x8*)(o + h * 128) = ov;
    }
}

// ============ layer-2 gather + bias + ELU, FUSED mean-pool via block LDS reduction ============
__global__ __launch_bounds__(256) void k_gat2(const int* __restrict__ start,
                                              const int* __restrict__ sums,
                                              const unsigned short* __restrict__ csr,
                                              const float* __restrict__ a_s,
                                              const float* __restrict__ a_d,
                                              const _Float16* __restrict__ xh2,
                                              const float* __restrict__ b2,
                                              const int* __restrict__ batch,
                                              float* __restrict__ pooled, int N)
{
    __shared__ float sm[16][128];
    __shared__ int sbat[16];
    const int grp = threadIdx.x >> 4;
    const int g16 = threadIdx.x & 15;
    const int d = blockIdx.x * 16 + grp;

    float vals[8];
    #pragma unroll
    for (int j = 0; j < 8; ++j) vals[j] = 0.f;

    if (d < N) {
        int jb = d >> 10;
        int p0 = 0;
        for (int b = 0; b < jb; ++b) p0 += sums[b];
        int p1 = p0 + ((((d + 1) >> 10) != jb) ? sums[jb] : 0);
        int beg = start[d] + p0, end = start[d + 1] + p1;
        int deg = end - beg;
        float ad = a_d[d];
        float sum = 0.f;
        f32x2 acc[4] = {};
        const _Float16* xb = xh2 + g16 * 8;

        for (int base = 0; base < deg; base += 16) {
            int nch = deg - base; if (nch > 16) nch = 16;
            int s = 0; float e = 0.f;
            if (g16 < nch) {
                s = csr[beg + base + g16];
                e = __expf(leaky(a_s[s] + ad));
                sum += e;
            }
            int t = 0;
            for (; t + 8 <= nch; t += 8) {
                int si[8];
                #pragma unroll
                for (int u = 0; u < 8; ++u) si[u] = __shfl(s, t + u, 16);
                f16x8 hv[8];
                #pragma unroll
                for (int u = 0; u < 8; ++u) hv[u] = *(const f16x8*)(xb + (size_t)si[u] * 128);
                #pragma unroll
                for (int u = 0; u < 8; ++u) {
                    float w = __shfl(e, t + u, 16);
                    #pragma unroll
                    for (int p = 0; p < 4; ++p) {
                        f32x2 v = { (float)hv[u][2*p], (float)hv[u][2*p+1] };
                        acc[p] += w * v;
                    }
                }
            }
            for (; t + 4 <= nch; t += 4) {
                int sA = __shfl(s, t, 16),     sB = __shfl(s, t + 1, 16);
                int sC = __shfl(s, t + 2, 16), sD = __shfl(s, t + 3, 16);
                f16x8 hA = *(const f16x8*)(xb + (size_t)sA * 128);
                f16x8 hB = *(const f16x8*)(xb + (size_t)sB * 128);
                f16x8 hC = *(const f16x8*)(xb + (size_t)sC * 128);
                f16x8 hD = *(const f16x8*)(xb + (size_t)sD * 128);
                float wA = __shfl(e, t, 16),     wB = __shfl(e, t + 1, 16);
                float wC = __shfl(e, t + 2, 16), wD = __shfl(e, t + 3, 16);
                #pragma unroll
                for (int p = 0; p < 4; ++p) {
                    f32x2 vA = { (float)hA[2*p], (float)hA[2*p+1] };
                    f32x2 vB = { (float)hB[2*p], (float)hB[2*p+1] };
                    f32x2 vC = { (float)hC[2*p], (float)hC[2*p+1] };
                    f32x2 vD = { (float)hD[2*p], (float)hD[2*p+1] };
                    acc[p] += wA * vA + wB * vB + wC * vC + wD * vD;
                }
            }
            for (; t < nch; ++t) {
                int   si = __shfl(s, t, 16);
                float w  = __shfl(e, t, 16);
                f16x8 hv = *(const f16x8*)(xb + (size_t)si * 128);
                #pragma unroll
                for (int p = 0; p < 4; ++p) {
                    f32x2 v = { (float)hv[2*p], (float)hv[2*p+1] };
                    acc[p] += w * v;
                }
            }
        }
        #pragma unroll
        for (int o = 1; o < 16; o <<= 1) sum += __shfl_xor(sum, o, 16);
        float inv = 1.f / (sum + 1e-16f);
        #pragma unroll
        for (int p = 0; p < 4; ++p) {
            vals[2 * p]     = elu(acc[p].x * inv + b2[g16 * 8 + 2 * p]);
            vals[2 * p + 1] = elu(acc[p].y * inv + b2[g16 * 8 + 2 * p + 1]);
        }
        if (g16 == 0) sbat[grp] = batch[d];
    } else {
        if (g16 == 0) sbat[grp] = -1;
    }
    #pragma unroll
    for (int j = 0; j < 8; ++j) sm[grp][g16 * 8 + j] = vals[j];
    __syncthreads();

    // 128 threads run the poolA run-length logic over the 16 staged rows
    if (threadIdx.x < 128) {
        int c = threadIdx.x;
        float acc = 0.f;
        int g = sbat[0];
        #pragma unroll
        for (int r = 0; r < 16; ++r) {
            int bg = sbat[r];
            if (bg < 0) break;
            if (bg != g) { atomicAdd(&pooled[(size_t)g * 128 + c], acc); acc = 0.f; g = bg; }
            acc += sm[r][c];
        }
        atomicAdd(&pooled[(size_t)g * 128 + c], acc);
    }
}

// ============ head: mean + relu(pooled@Wh1^T+bh1) @ Wh2^T + bh2 ============
__global__ __launch_bounds__(128) void k_head(const float* __restrict__ pooled,
                                              const int* __restrict__ gstart,
                                              const float* __restrict__ Wh1,
                                              const float* __restrict__ bh1,
                                              const float* __restrict__ Wh2,
                                              const float* __restrict__ bh2,
                                              float* __restrict__ out)
{
    int g = blockIdx.x, c = threadIdx.x;
    __shared__ float p[128];
    __shared__ float red[128];
    float cf = (float)(gstart[g + 1] - gstart[g]); cf = cf > 1.f ? cf : 1.f;
    p[c] = pooled[(size_t)g * 128 + c] / cf;
    __syncthreads();
    float z = bh1[c];
    for (int k = 0; k < 128; ++k) z += p[k] * Wh1[c * 128 + k];
    z = z > 0.f ? z : 0.f;
    red[c] = z * Wh2[c];
    __syncthreads();
    for (int st = 64; st > 0; st >>= 1) { if (c < st) red[c] += red[c + st]; __syncthreads(); }
    if (c == 0) out[g] = red[0] + bh2[0];
}

// ============ launch ============
extern "C" void kernel_launch(void* const* d_in, const int* in_sizes, int n_in,
                              void* d_out, int out_size, void* d_ws, size_t ws_size,
                              hipStream_t stream)
{
    const float* x   = (const float*)d_in[0];
    const int*   ei  = (const int*)d_in[1];
    const int*   bat = (const int*)d_in[2];
    const float* W1  = (const float*)d_in[3];
    const float* as1 = (const float*)d_in[4];
    const float* ad1 = (const float*)d_in[5];
    const float* b1  = (const float*)d_in[6];
    const float* W2  = (const float*)d_in[7];
    const float* as2 = (const float*)d_in[8];
    const float* ad2 = (const float*)d_in[9];
    const float* b2  = (const float*)d_in[10];
    const float* Wh1 = (const float*)d_in[11];
    const float* bh1 = (const float*)d_in[12];
    const float* Wh2 = (const float*)d_in[13];
    const float* bh2 = (const float*)d_in[14];
    float* out = (float*)d_out;

    const int N  = in_sizes[0] / 128;
    const int E  = in_sizes[1] / 2;
    const int Ep = E + N;
    const int G  = 128;
    const int nscan = (N + 1 + 1023) / 1024;

    char* w = (char*)d_ws;
    size_t off = 0;
    auto alloc = [&](size_t bytes) -> char* {
        char* p = w + off; off += (bytes + 511) & ~(size_t)511; return p;
    };
    _Float16* x_h  = (_Float16*)alloc((size_t)N * 128 * 2);
    _Float16* agg  = (_Float16*)alloc((size_t)N * 512 * 2);
    _Float16* xh2h = (_Float16*)alloc((size_t)N * 128 * 2);
    float*    As1  = (float*)alloc((size_t)N * 4 * 4);
    float*    Ad1  = (float*)alloc((size_t)N * 4 * 4);
    float*    As2  = (float*)alloc((size_t)N * 4);
    float*    Ad2  = (float*)alloc((size_t)N * 4);
    _Float16* W1hi = (_Float16*)alloc(65536 * 2);
    _Float16* W1lo = (_Float16*)alloc(65536 * 2);
    _Float16* W2hi = (_Float16*)alloc(65536 * 2);
    _Float16* W2lo = (_Float16*)alloc(65536 * 2);
    int* startb = (int*)alloc((size_t)(N + 1) * 4);
    unsigned short* csr  = (unsigned short*)alloc((size_t)Ep * 2);
    unsigned short* rank = (unsigned short*)alloc((size_t)Ep * 2);
    int* sums   = (int*)alloc(4096);
    int* gstart = (int*)alloc((size_t)(G + 1) * 4);
    float* pooled = (float*)alloc((size_t)G * 128 * 4);   // zeroed by k_gemm12 epilogue
    char* zbase = w + off;                                // zero-init group (deg, w_s1, w_d1)
    int*   deg    = (int*)alloc((size_t)N * 4);
    float* w_s1 = (float*)alloc(512 * 4);
    float* w_d1 = (float*)alloc(512 * 4);
    size_t zbytes = (size_t)((w + off) - zbase);

    hipMemsetAsync(zbase, 0, zbytes, stream);

    // 1) fused: weight split + parallel attn fold (atomic) + CSR degree count + graph boundaries
    int nbc = (Ep + 255) / 256, nbg = (N + 255) / 256;
    k_front<<<576 + nbc + nbg, 256, 0, stream>>>(W1, W2, as1, ad1, W1hi, W1lo, W2hi, W2lo,
                                                 w_s1, w_d1, ei, deg, rank, bat, gstart,
                                                 E, Ep, N, G, nbc);
    // 2) fused: degree scan (block-local) || layer-1 logits + fp16 x
    k_scan_attn<<<nscan + (N + 15) / 16, 1024, 0, stream>>>(deg, startb, sums, N + 1, N, nscan,
                                                            x, w_s1, w_d1, As1, Ad1, x_h);
    // 3) CSR fill (adds block prefix inline)
    k_fill<<<(Ep + 255) / 256, 256, 0, stream>>>(ei, startb, rank, sums, nscan, csr, E, Ep);
    // 4) layer-1 gather -> agg fp16 [N, 4*128]
    k_gat1<<<(N + 15) / 16, 256, 0, stream>>>(startb, sums, csr, As1, Ad1, x_h, agg, N);
    // 5) FUSED: h1 = ELU(blockdiag proj + b1) [LDS only] ; xh2 = h1 @ W2^T ; attn2 logits ; zero pooled
    k_gemm12<<<(N + 127) / 128, 256, 0, stream>>>(agg, W1hi, W1lo, b1, W2hi, W2lo,
                                                  xh2h, as2, ad2, As2, Ad2, pooled, N);
    // 6) layer-2 gather + bias + ELU + fused mean-pool (block LDS reduction, few atomics)
    k_gat2<<<(N + 15) / 16, 256, 0, stream>>>(startb, sums, csr, As2, Ad2, xh2h, b2, bat, pooled, N);
    // 7) MLP head
    k_head<<<G, 128, 0, stream>>>(pooled, gstart, Wh1, bh1, Wh2, bh2, out);
}